// Round 10
// baseline (127.053 us; speedup 1.0000x reference)
//
#include <hip/hip_runtime.h>
#include <hip/hip_bf16.h>
#include <stdint.h>

#define N_SAMP 8192
#define D_TOW  128
#define D_HID  128

typedef __bf16 bf16x8 __attribute__((ext_vector_type(8)));
typedef float  f32x4  __attribute__((ext_vector_type(4)));
typedef float  f32x2  __attribute__((ext_vector_type(2)));

__device__ __forceinline__ ushort f2bf(float f) {
  union { float f; uint32_t u; } c; c.f = f;
  uint32_t u = c.u;
  return (ushort)((u + 0x7FFFu + ((u >> 16) & 1u)) >> 16);  // RNE
}

// sigmoid via raw HW ops: v_exp_f32 + v_rcp_f32.
__device__ __forceinline__ float fast_sigmoid(float p) {
  float e = __builtin_amdgcn_exp2f(p * -1.442695040888963f);
  return __builtin_amdgcn_rcpf(1.0f + e);
}

// fp32 -> bf16 convert. W0 is pre-scaled by -log2(e) so the towers MFMA
// directly produces exp2 arguments. x path writes a per-block "saw
// non-binary" flag UNCONDITIONALLY (no memset needed); flagArr = 256 ints.
__global__ __launch_bounds__(1024) void prep_kernel(
    const float* __restrict__ x, const float* __restrict__ w0,
    ushort* __restrict__ xb, ushort* __restrict__ w0b,
    int* __restrict__ flagArr) {
  const int NX4 = (N_SAMP * D_TOW) / 4;  // 262144 -> x-blocks are bid 0..255
  int bid = blockIdx.x;
  int tid = threadIdx.x;
  int t = bid * 1024 + tid;
  if (bid < 256) {
    __shared__ int sbad;
    if (tid == 0) sbad = 0;
    float4 v = ((const float4*)x)[t];
    bool bad = !(((v.x == 0.f) || (v.x == 1.f)) &&
                 ((v.y == 0.f) || (v.y == 1.f)) &&
                 ((v.z == 0.f) || (v.z == 1.f)) &&
                 ((v.w == 0.f) || (v.w == 1.f)));
    ushort4 o;
    o.x = f2bf(v.x); o.y = f2bf(v.y); o.z = f2bf(v.z); o.w = f2bf(v.w);
    ((ushort4*)xb)[t] = o;
    __syncthreads();
    if (__ballot(bad) != 0ull && (tid & 63) == 0) sbad = 1;
    __syncthreads();
    if (tid == 0) flagArr[bid] = sbad;
  } else {
    const float c = -1.442695040888963f;
    int j = t - NX4;
    float4 v = ((const float4*)w0)[j];
    ushort4 o;
    o.x = f2bf(c * v.x); o.y = f2bf(c * v.y);
    o.z = f2bf(c * v.z); o.w = f2bf(c * v.w);
    ((ushort4*)w0b)[j] = o;
  }
}

__device__ __forceinline__ void g2l16(const void* g, void* l) {
  __builtin_amdgcn_global_load_lds(
      (const __attribute__((address_space(1))) void*)g,
      (__attribute__((address_space(3))) void*)l, 16, 0, 0);
}

// BEST-MEASURED configuration (R3: towers 57.7us, e2e 119.9us), restored
// exactly. One block = one tower k x one 128-row chunk of samples.
// X and W0_k staged in LDS in TWO k-half phases of 16 KB each: 33.5 KB
// total -> 4 blocks/CU at the 128-reg cap (64 VGPR + 64 acc AGPR,
// __launch_bounds__(256,4); (512,6) spills -> 7x regression, R4).
// LDS rows are 64 bf16 (8x16B slots); slot holds global chunk slot^(row&7)
// -> conflict-free ds_read_b128 (measured 0 conflict cycles).
// Block mapping: per XCD, k is the FAST index -> 16 towers sharing an
// n-chunk run concurrently -> out[n][k0..k0+15] write-merges in L2
// (FETCH 10.3 MB / WRITE 4.1 MB ~= ideal; persistent grids break this:
// 290 MB L2-miss pathology, R5/R6).
// Falsified levers (kept OUT): counted-vmcnt quarter pipeline (R7,
// neutral), 256-sample geometry (R8, -12%), phase stagger (R9, neutral),
// global-direct B-frags (R1, -67%).
__global__ __launch_bounds__(256, 4) void towers_kernel(
    const ushort* __restrict__ xb, const ushort* __restrict__ w0b,
    const float* __restrict__ b0, const float* __restrict__ w1,
    const float* __restrict__ b1, const int* __restrict__ flagArr,
    float* __restrict__ out) {
  __shared__ __align__(16) ushort sX[128 * 64];  // 16 KB
  __shared__ __align__(16) ushort sW[128 * 64];  // 16 KB
  __shared__ float sRed[128][2];
  __shared__ int sBadW[4];

  int bid = blockIdx.x;
  int xcd = bid & 7;
  int idx = bid >> 3;            // 0..1023 per XCD
  int k  = xcd * 16 + (idx & 15);
  int n0 = (idx >> 4) * 128;

  int tid = threadIdx.x;
  int lane = tid & 63;
  int wave = tid >> 6;
  int q = lane >> 4;      // quad index (bits 4-5)
  int cl = lane & 15;

  const ushort* xg = xb + (size_t)n0 * 128;  // [128][128] row-major bf16
  const ushort* wg = w0b + k * (128 * 128);  // W0_k: [h][d] row-major bf16

  int R  = (wave >> 1) * 64;   // n-quadrant
  int Ch = (wave & 1) * 64;    // h-half

  int rowl = lane >> 3;   // 0..7 within a 1KB staging chunk
  int slot = lane & 7;

  // Issue phase-0 staging first so the latency hides under flag read +
  // bias load + acc init. LDS dest = uniform base + lane*16 (HW rule);
  // XOR swizzle applied to the *global source* chunk: LDS[row][c] holds
  // global chunk c^(row&7).
#pragma unroll
  for (int i = 0; i < 4; ++i) {
    int row = wave * 32 + i * 8 + rowl;
    int c = slot ^ (row & 7);
    int goff = row * 128 + c * 8;
    int lbase = (wave * 32 + i * 8) * 128;
    g2l16(xg + goff, (char*)sX + lbase);
    g2l16(wg + goff, (char*)sW + lbase);
  }

  // Binary-flag OR-reduce (256 ints = 1 KB).
  int anyb = flagArr[tid];
  unsigned long long mb = __ballot(anyb != 0);
  if (lane == 0) sBadW[wave] = (mb != 0ull) ? 1 : 0;

  // acc init = -log2e * b0 (bias folded into MFMA accumulator).
  // C layout: col = n = R + nf*16 + cl ; row = h = Ch + hf*16 + q*4 + r.
  const float cn = -1.442695040888963f;
  f32x4 acc[4][4];             // [hf][nf]
#pragma unroll
  for (int hf = 0; hf < 4; ++hf) {
    int h = k * 128 + Ch + hf * 16 + q * 4;
    f32x4 bbs = *(const f32x4*)&b0[h] * cn;
#pragma unroll
    for (int nf = 0; nf < 4; ++nf)
      acc[hf][nf] = bbs;
  }

  // Row base byte-offsets (LDS row = 128 B).
  int aBase[4], bBase[4];
#pragma unroll
  for (int f = 0; f < 4; ++f) {
    aBase[f] = (Ch + f * 16 + cl) * 128;     // W row = h
    bBase[f] = (R + f * 16 + cl) * 128;      // X row = n
  }

#pragma unroll
  for (int kb = 0; kb < 2; ++kb) {
    __syncthreads();   // staged data visible (compiler drains vmcnt first)

#pragma unroll
    for (int t = 0; t < 2; ++t) {  // 2 x K=32 per phase
      int ch = ((t * 4 + q) ^ (cl & 7)) << 4;   // swizzled 16B slot offset
      bf16x8 a[4], b[4];
#pragma unroll
      for (int hf = 0; hf < 4; ++hf)
        a[hf] = *(const bf16x8*)((const char*)sW + aBase[hf] + ch);
#pragma unroll
      for (int nf = 0; nf < 4; ++nf)
        b[nf] = *(const bf16x8*)((const char*)sX + bBase[nf] + ch);
      __builtin_amdgcn_s_setprio(1);
#pragma unroll
      for (int hf = 0; hf < 4; ++hf)
#pragma unroll
        for (int nf = 0; nf < 4; ++nf)
          acc[hf][nf] = __builtin_amdgcn_mfma_f32_16x16x32_bf16(
              a[hf], b[nf], acc[hf][nf], 0, 0, 0);
      __builtin_amdgcn_s_setprio(0);
    }

    if (kb == 0) {
      __syncthreads();   // everyone done reading phase-0 LDS
      // Stage the second k-half [64..127] of both tiles.
#pragma unroll
      for (int i = 0; i < 4; ++i) {
        int row = wave * 32 + i * 8 + rowl;
        int c = slot ^ (row & 7);
        int goff = row * 128 + 64 + c * 8;
        int lbase = (wave * 32 + i * 8) * 128;
        g2l16(xg + goff, (char*)sX + lbase);
        g2l16(wg + goff, (char*)sW + lbase);
      }
    }
  }

  // Epilogue: sigmoid = rcp(1 + exp2(acc)); rcps paired (1.5 trans/elem);
  // mul/fma paths paired as f32x2 for v_pk_*_f32. w1 loaded here (not
  // hoisted) to keep arch VGPR at 64 under the 128-reg cap.
  f32x2 s2[4] = {{0.f, 0.f}, {0.f, 0.f}, {0.f, 0.f}, {0.f, 0.f}};
#pragma unroll
  for (int hf = 0; hf < 4; ++hf) {
    int h = k * 128 + Ch + hf * 16 + q * 4;
    f32x4 wv = *(const f32x4*)&w1[h];
    f32x2 wa = {wv[0], wv[1]};
    f32x2 wb = {wv[2], wv[3]};
#pragma unroll
    for (int nf = 0; nf < 4; ++nf) {
      f32x4 qv = acc[hf][nf];
      f32x2 dA = {1.0f + __builtin_amdgcn_exp2f(qv[0]),
                  1.0f + __builtin_amdgcn_exp2f(qv[1])};
      f32x2 dB = {1.0f + __builtin_amdgcn_exp2f(qv[2]),
                  1.0f + __builtin_amdgcn_exp2f(qv[3])};
      float rA = __builtin_amdgcn_rcpf(dA[0] * dA[1]);
      float rB = __builtin_amdgcn_rcpf(dB[0] * dB[1]);
      f32x2 cA = (f32x2){dA[1], dA[0]} * (f32x2){rA, rA};
      f32x2 cB = (f32x2){dB[1], dB[0]} * (f32x2){rB, rB};
      s2[nf] += wa * cA;
      s2[nf] += wb * cB;
    }
  }
  float s[4];
#pragma unroll
  for (int nf = 0; nf < 4; ++nf)
    s[nf] = s2[nf][0] + s2[nf][1];

#pragma unroll
  for (int m = 16; m <= 32; m <<= 1)
#pragma unroll
    for (int nf = 0; nf < 4; ++nf)
      s[nf] += __shfl_xor(s[nf], m, 64);

  if (q == 0) {
#pragma unroll
    for (int nf = 0; nf < 4; ++nf)
      sRed[R + nf * 16 + cl][wave & 1] = s[nf];
  }
  __syncthreads();

  if (tid < 128) {
    int anyBad = sBadW[0] | sBadW[1] | sBadW[2] | sBadW[3];
    float v = sRed[tid][0] + sRed[tid][1] + b1[k];
    if (anyBad == 0) v = fast_sigmoid(v);  // binary-input path
    out[(size_t)(n0 + tid) * D_TOW + k] = v;
  }
}

extern "C" void kernel_launch(void* const* d_in, const int* in_sizes, int n_in,
                              void* d_out, int out_size, void* d_ws, size_t ws_size,
                              hipStream_t stream) {
  const float* x  = (const float*)d_in[0];
  const float* w0 = (const float*)d_in[1];
  const float* b0 = (const float*)d_in[2];
  const float* w1 = (const float*)d_in[3];
  const float* b1 = (const float*)d_in[4];
  float* out = (float*)d_out;

  char* ws = (char*)d_ws;
  int* flagArr = (int*)ws;                                   // 1 KB
  ushort* xb  = (ushort*)(ws + 4096);                        // 2 MB
  ushort* w0b = (ushort*)(ws + 4096 + N_SAMP * D_TOW * 2);   // 4 MB

  int total = (N_SAMP * D_TOW + D_TOW * D_HID * D_TOW) / 4;  // 786432 float4
  prep_kernel<<<total / 1024, 1024, 0, stream>>>(x, w0, xb, w0b, flagArr);

  towers_kernel<<<8192, 256, 0, stream>>>(xb, w0b, b0, w1, b1, flagArr, out);
}